// Round 1
// baseline (403.507 us; speedup 1.0000x reference)
//
#include <hip/hip_runtime.h>
#include <math.h>

// CasperNet: B=131072 rows, D=256 inputs, H=64 cascade neurons, O=10 outputs.
// One thread per row. Decomposition:
//   a[i]   = b_h[i] + W_h[i,0:256]·x            (parallel GEMM part)
//   h_i    = sigmoid(a_i + sum_{j<i} U[i,j]h_j) (sequential, U=W_h[:,256+j])
//   out[o] = b_out[o] + Wo[o,0:256]·x + sum_i Wo[o,256+i]·h_i
// All per-thread arrays statically indexed (full unroll) to stay in VGPRs.

#define DIMD 256
#define DIMH 64
#define DIMO 10
#define DT   320   // D + H
#define KC   16    // k-chunk: one 64B cache line per thread per chunk

__global__ __launch_bounds__(256, 2) void caspernet_kernel(
    const float* __restrict__ x,    // [B, 256]
    const float* __restrict__ Wh,   // [64, 320]
    const float* __restrict__ bh,   // [64]
    const float* __restrict__ Wo,   // [10, 320]
    const float* __restrict__ bo,   // [10]
    float* __restrict__ out,        // [B, 10]
    int B)
{
    const int row = blockIdx.x * blockDim.x + threadIdx.x;
    if (row >= B) return;
    const float* xr = x + (size_t)row * DIMD;

    float a[DIMH];
    #pragma unroll
    for (int i = 0; i < DIMH; ++i) a[i] = bh[i];
    float o_[DIMO];
    #pragma unroll
    for (int j = 0; j < DIMO; ++j) o_[j] = bo[j];

    // ---- GEMM part: stream x row in 64B chunks, accumulate 64+10 dots ----
    for (int c = 0; c < DIMD; c += KC) {
        float xv[KC];
        #pragma unroll
        for (int q = 0; q < KC / 4; ++q) {
            const float4 v = *reinterpret_cast<const float4*>(xr + c + 4 * q);
            xv[4*q+0] = v.x; xv[4*q+1] = v.y; xv[4*q+2] = v.z; xv[4*q+3] = v.w;
        }
        #pragma unroll
        for (int i = 0; i < DIMH; ++i) {
            const float* wr = Wh + i * DT + c;   // uniform address -> s_load
            #pragma unroll
            for (int k = 0; k < KC; ++k)
                a[i] = fmaf(xv[k], wr[k], a[i]);
        }
        #pragma unroll
        for (int j = 0; j < DIMO; ++j) {
            const float* wr = Wo + j * DT + c;
            #pragma unroll
            for (int k = 0; k < KC; ++k)
                o_[j] = fmaf(xv[k], wr[k], o_[j]);
        }
    }

    // ---- cascade recurrence: fully unrolled (static reg indexing) ----
    #pragma unroll
    for (int i = 0; i < DIMH; ++i) {
        const float s = a[i];
        const float h = 1.0f / (1.0f + __expf(-s));
        #pragma unroll
        for (int j = i + 1; j < DIMH; ++j)
            a[j] = fmaf(Wh[j * DT + DIMD + i], h, a[j]);   // scatter to future neurons
        #pragma unroll
        for (int j = 0; j < DIMO; ++j)
            o_[j] = fmaf(Wo[j * DT + DIMD + i], h, o_[j]);
    }

    // ---- store 10 f32 as 5x float2 (row*40B is 8B-aligned) ----
    float2* op = reinterpret_cast<float2*>(out + (size_t)row * DIMO);
    #pragma unroll
    for (int j = 0; j < DIMO / 2; ++j)
        op[j] = make_float2(o_[2*j], o_[2*j+1]);
}

extern "C" void kernel_launch(void* const* d_in, const int* in_sizes, int n_in,
                              void* d_out, int out_size, void* d_ws, size_t ws_size,
                              hipStream_t stream) {
    const float* x  = (const float*)d_in[0];
    const float* Wh = (const float*)d_in[1];
    const float* bh = (const float*)d_in[2];
    const float* Wo = (const float*)d_in[3];
    const float* bo = (const float*)d_in[4];
    float* out = (float*)d_out;

    const int B = in_sizes[0] / DIMD;          // 131072
    const int block = 256;
    const int grid = (B + block - 1) / block;  // 512 blocks -> 2 per CU

    hipLaunchKernelGGL(caspernet_kernel, dim3(grid), dim3(block), 0, stream,
                       x, Wh, bh, Wo, bo, out, B);
}

// Round 2
// 337.548 us; speedup vs baseline: 1.1954x; 1.1954x over previous
//
#include <hip/hip_runtime.h>
#include <math.h>

// CasperNet R2: B=131072 rows, D=256, H=64 cascade neurons, O=10 outputs.
// Changes vs R1 (403us, VALUBusy 28%, occupancy 24%):
//  - 2-way k-split: lane pair (2r,2r+1) shares row r, each does half the
//    D=256 dot products, combined via shfl_xor(1). Doubles wave count.
//  - block=1024 covering 512 rows, grid=256 -> 16 waves/CU (50% occupancy).
//  - All weights staged in LDS fp32 (~93.5KB, 1 block/CU) and read as
//    lane-uniform broadcasts (2 distinct addrs/wave = free 2-way).
//  - U (cascade coupling) and Wo_h stored TRANSPOSED in LDS so the
//    unrolled cascade reads contiguous rows (mergeable ds_reads).

#define DIMD 256
#define DIMH 64
#define DIMO 10
#define DT   320          // D + H
#define BLOCK 1024
#define UTS  66           // Ut row stride (pad: write conflicts 2-way = free)

__global__ __launch_bounds__(BLOCK) void caspernet_kernel(
    const float* __restrict__ x,    // [B, 256]
    const float* __restrict__ Wh,   // [64, 320]
    const float* __restrict__ bh,   // [64]
    const float* __restrict__ Wo,   // [10, 320]
    const float* __restrict__ bo,   // [10]
    float* __restrict__ out,        // [B, 10]
    int B)
{
    __shared__ float sWhX[DIMH * DIMD];   // Wh[:, 0:256]        64KB
    __shared__ float sWoX[DIMO * DIMD];   // Wo[:, 0:256]        10KB
    __shared__ float sUt[DIMH * UTS];     // Ut[i][j]=Wh[j][256+i] 16.5KB
    __shared__ float sWohT[DIMH * 12];    // WohT[i][j]=Wo[j][256+i] 3KB

    const int tid = threadIdx.x;

    // ---- stage weights into LDS (coalesced float4 for the big arrays) ----
    {
        float4* dW = (float4*)sWhX;
        for (int idx = tid; idx < DIMH * (DIMD / 4); idx += BLOCK) {
            const int r = idx >> 6, c = idx & 63;   // 64 float4 per row
            dW[idx] = *reinterpret_cast<const float4*>(Wh + r * DT + c * 4);
        }
        float4* dO = (float4*)sWoX;
        for (int idx = tid; idx < DIMO * (DIMD / 4); idx += BLOCK) {
            const int r = idx >> 6, c = idx & 63;
            dO[idx] = *reinterpret_cast<const float4*>(Wo + r * DT + c * 4);
        }
        // U transpose: idx = j*64 + i  (i fastest -> coalesced global reads,
        // LDS writes stride UTS -> 2-way bank alias = free)
        for (int idx = tid; idx < DIMH * DIMH; idx += BLOCK) {
            const int j = idx >> 6, i = idx & 63;
            sUt[i * UTS + j] = Wh[j * DT + DIMD + i];
        }
        for (int idx = tid; idx < DIMH * DIMO; idx += BLOCK) {
            const int i = idx / DIMO, j = idx % DIMO;
            sWohT[i * 12 + j] = Wo[j * DT + DIMD + i];
        }
    }
    __syncthreads();

    const int gtid = blockIdx.x * BLOCK + tid;
    const int row = gtid >> 1;          // 2 threads per row
    const int p   = gtid & 1;           // k-half: [p*128, p*128+128)
    if (row >= B) return;
    const float* xr = x + (size_t)row * DIMD + p * 128;

    float a[DIMH];
    #pragma unroll
    for (int i = 0; i < DIMH; ++i) a[i] = 0.0f;
    float o_[DIMO];
    #pragma unroll
    for (int j = 0; j < DIMO; ++j) o_[j] = 0.0f;

    // ---- GEMM part over this thread's 128-wide k-half ----
    const float* whb = sWhX + p * 128;
    const float* wob = sWoX + p * 128;
    for (int c = 0; c < 128; c += 16) {
        float xs[16];
        #pragma unroll
        for (int q = 0; q < 4; ++q) {
            const float4 v = *reinterpret_cast<const float4*>(xr + c + 4 * q);
            xs[4*q+0] = v.x; xs[4*q+1] = v.y; xs[4*q+2] = v.z; xs[4*q+3] = v.w;
        }
        #pragma unroll
        for (int i = 0; i < DIMH; ++i) {
            const float* w = whb + i * DIMD + c;   // broadcast ds_read
            #pragma unroll
            for (int k = 0; k < 16; ++k)
                a[i] = fmaf(xs[k], w[k], a[i]);
        }
        #pragma unroll
        for (int j = 0; j < DIMO; ++j) {
            const float* w = wob + j * DIMD + c;
            #pragma unroll
            for (int k = 0; k < 16; ++k)
                o_[j] = fmaf(xs[k], w[k], o_[j]);
        }
    }

    // ---- combine the two k-halves (both lanes end with the full sums) ----
    #pragma unroll
    for (int i = 0; i < DIMH; ++i) a[i] += __shfl_xor(a[i], 1, 64);
    #pragma unroll
    for (int j = 0; j < DIMO; ++j) o_[j] += __shfl_xor(o_[j], 1, 64);
    #pragma unroll
    for (int i = 0; i < DIMH; ++i) a[i] += bh[i];
    #pragma unroll
    for (int j = 0; j < DIMO; ++j) o_[j] += bo[j];

    // ---- cascade recurrence (redundant on both lanes of the pair) ----
    #pragma unroll
    for (int i = 0; i < DIMH; ++i) {
        const float h = 1.0f / (1.0f + __expf(-a[i]));
        const float* ut = sUt + i * UTS;        // contiguous, broadcast
        #pragma unroll
        for (int j = i + 1; j < DIMH; ++j)
            a[j] = fmaf(ut[j], h, a[j]);
        const float* wt = sWohT + i * 12;
        #pragma unroll
        for (int j = 0; j < DIMO; ++j)
            o_[j] = fmaf(wt[j], h, o_[j]);
    }

    // ---- store (lane p==0 of each pair writes the row) ----
    if (p == 0) {
        float2* op = reinterpret_cast<float2*>(out + (size_t)row * DIMO);
        #pragma unroll
        for (int j = 0; j < DIMO / 2; ++j)
            op[j] = make_float2(o_[2*j], o_[2*j+1]);
    }
}

extern "C" void kernel_launch(void* const* d_in, const int* in_sizes, int n_in,
                              void* d_out, int out_size, void* d_ws, size_t ws_size,
                              hipStream_t stream) {
    const float* x  = (const float*)d_in[0];
    const float* Wh = (const float*)d_in[1];
    const float* bh = (const float*)d_in[2];
    const float* Wo = (const float*)d_in[3];
    const float* bo = (const float*)d_in[4];
    float* out = (float*)d_out;

    const int B = in_sizes[0] / DIMD;                  // 131072
    const int threads_total = B * 2;                   // 2 threads per row
    const int grid = (threads_total + BLOCK - 1) / BLOCK;  // 256

    hipLaunchKernelGGL(caspernet_kernel, dim3(grid), dim3(BLOCK), 0, stream,
                       x, Wh, bh, Wo, bo, out, B);
}

// Round 3
// 248.199 us; speedup vs baseline: 1.6257x; 1.3600x over previous
//
#include <hip/hip_runtime.h>
#include <math.h>

// CasperNet R3: B=131072 rows, D=256, H=64 cascade, O=10.
// vs R2 (337us): the killer was VGPR spill (VGPR_Count=64 cap from
// __launch_bounds__(1024) while ~105 regs live -> 239MB scratch writes).
//  Fix 1: __launch_bounds__(1024, 4): LDS (93.5KB) caps us at 1 block/CU
//         = 4 waves/SIMD anyway, so allow the full 128-VGPR budget.
//  Fix 2: k-split by interleaved 16-float chunks (p*64B) instead of
//         128-float halves: pair's weight addrs hit banks 0-15 vs 16-31
//         (conflict-free, was 2-way same-bank), and the pair's x loads
//         form one contiguous 128B segment.

#define DIMD 256
#define DIMH 64
#define DIMO 10
#define DT   320          // D + H
#define BLOCK 1024
#define UTS  66           // Ut row stride (pad)

__global__ __launch_bounds__(BLOCK, 4) void caspernet_kernel(
    const float* __restrict__ x,    // [B, 256]
    const float* __restrict__ Wh,   // [64, 320]
    const float* __restrict__ bh,   // [64]
    const float* __restrict__ Wo,   // [10, 320]
    const float* __restrict__ bo,   // [10]
    float* __restrict__ out,        // [B, 10]
    int B)
{
    __shared__ float sWhX[DIMH * DIMD];   // Wh[:, 0:256]          64KB
    __shared__ float sWoX[DIMO * DIMD];   // Wo[:, 0:256]          10KB
    __shared__ float sUt[DIMH * UTS];     // Ut[i][j]=Wh[j][256+i] 16.5KB
    __shared__ float sWohT[DIMH * 12];    // WohT[i][j]=Wo[j][256+i] 3KB

    const int tid = threadIdx.x;

    // ---- stage weights into LDS ----
    {
        float4* dW = (float4*)sWhX;
        #pragma unroll
        for (int idx = tid; idx < DIMH * (DIMD / 4); idx += BLOCK) {
            const int r = idx >> 6, c = idx & 63;
            dW[idx] = *reinterpret_cast<const float4*>(Wh + r * DT + c * 4);
        }
        float4* dO = (float4*)sWoX;
        for (int idx = tid; idx < DIMO * (DIMD / 4); idx += BLOCK) {
            const int r = idx >> 6, c = idx & 63;
            dO[idx] = *reinterpret_cast<const float4*>(Wo + r * DT + c * 4);
        }
        for (int idx = tid; idx < DIMH * DIMH; idx += BLOCK) {
            const int j = idx >> 6, i = idx & 63;
            sUt[i * UTS + j] = Wh[j * DT + DIMD + i];
        }
        for (int idx = tid; idx < DIMH * DIMO; idx += BLOCK) {
            const int i = idx / DIMO, j = idx % DIMO;
            sWohT[i * 12 + j] = Wo[j * DT + DIMD + i];
        }
    }
    __syncthreads();

    const int gtid = blockIdx.x * BLOCK + tid;
    const int row = gtid >> 1;          // 2 threads per row
    const int p   = gtid & 1;           // interleaved k-chunks: c*32 + p*16
    if (row >= B) return;
    const float* xr = x + (size_t)row * DIMD + p * 16;

    float a[DIMH];
    #pragma unroll
    for (int i = 0; i < DIMH; ++i) a[i] = 0.0f;
    float o_[DIMO];
    #pragma unroll
    for (int j = 0; j < DIMO; ++j) o_[j] = 0.0f;

    // ---- GEMM part: thread handles k in {c*32 + p*16 + 0..15}, c=0..7 ----
    const float* whb = sWhX + p * 16;
    const float* wob = sWoX + p * 16;
    for (int c = 0; c < 8; ++c) {
        float xs[16];
        #pragma unroll
        for (int q = 0; q < 4; ++q) {
            const float4 v = *reinterpret_cast<const float4*>(xr + c * 32 + 4 * q);
            xs[4*q+0] = v.x; xs[4*q+1] = v.y; xs[4*q+2] = v.z; xs[4*q+3] = v.w;
        }
        #pragma unroll
        for (int i = 0; i < DIMH; ++i) {
            const float* w = whb + i * DIMD + c * 32;  // banks p*16..p*16+15
            #pragma unroll
            for (int k = 0; k < 16; ++k)
                a[i] = fmaf(xs[k], w[k], a[i]);
        }
        #pragma unroll
        for (int j = 0; j < DIMO; ++j) {
            const float* w = wob + j * DIMD + c * 32;
            #pragma unroll
            for (int k = 0; k < 16; ++k)
                o_[j] = fmaf(xs[k], w[k], o_[j]);
        }
    }

    // ---- combine the two k-halves (both lanes get full sums) ----
    #pragma unroll
    for (int i = 0; i < DIMH; ++i) a[i] += __shfl_xor(a[i], 1, 64);
    #pragma unroll
    for (int j = 0; j < DIMO; ++j) o_[j] += __shfl_xor(o_[j], 1, 64);
    #pragma unroll
    for (int i = 0; i < DIMH; ++i) a[i] += bh[i];
    #pragma unroll
    for (int j = 0; j < DIMO; ++j) o_[j] += bo[j];

    // ---- cascade recurrence (redundant on both lanes; broadcast reads) ----
    #pragma unroll
    for (int i = 0; i < DIMH; ++i) {
        const float h = 1.0f / (1.0f + __expf(-a[i]));
        const float* ut = sUt + i * UTS;
        #pragma unroll
        for (int j = i + 1; j < DIMH; ++j)
            a[j] = fmaf(ut[j], h, a[j]);
        const float* wt = sWohT + i * 12;
        #pragma unroll
        for (int j = 0; j < DIMO; ++j)
            o_[j] = fmaf(wt[j], h, o_[j]);
    }

    // ---- store (lane p==0 writes the row) ----
    if (p == 0) {
        float2* op = reinterpret_cast<float2*>(out + (size_t)row * DIMO);
        #pragma unroll
        for (int j = 0; j < DIMO / 2; ++j)
            op[j] = make_float2(o_[2*j], o_[2*j+1]);
    }
}

extern "C" void kernel_launch(void* const* d_in, const int* in_sizes, int n_in,
                              void* d_out, int out_size, void* d_ws, size_t ws_size,
                              hipStream_t stream) {
    const float* x  = (const float*)d_in[0];
    const float* Wh = (const float*)d_in[1];
    const float* bh = (const float*)d_in[2];
    const float* Wo = (const float*)d_in[3];
    const float* bo = (const float*)d_in[4];
    float* out = (float*)d_out;

    const int B = in_sizes[0] / DIMD;                      // 131072
    const int threads_total = B * 2;
    const int grid = (threads_total + BLOCK - 1) / BLOCK;  // 256

    hipLaunchKernelGGL(caspernet_kernel, dim3(grid), dim3(BLOCK), 0, stream,
                       x, Wh, bh, Wo, bo, out, B);
}